// Round 7
// baseline (4632.784 us; speedup 1.0000x reference)
//
#include <hip/hip_runtime.h>
#include <math.h>

#define B_ 16
#define N_ 2048
#define KNN 20
#define BN_EPS 1e-5f
#define SLOPE 0.01f

typedef float f32x4 __attribute__((ext_vector_type(4)));
typedef _Float16 f16x8 __attribute__((ext_vector_type(8)));
typedef unsigned short ushort_t;

// ============================================================ xx = sum_d x^2
__global__ __launch_bounds__(256) void xx_kernel(const float* __restrict__ xin, long bstr, int D,
                                                 float* __restrict__ xx) {
  int i = blockIdx.x * 256 + threadIdx.x;
  if (i >= B_ * N_) return;
  int b = i >> 11, n = i & (N_ - 1);
  const float* p = xin + (long)b * bstr + n;
  float s = 0.f;
#pragma unroll 1
  for (int d = 0; d < D; ++d) { float v = p[(long)d * N_]; s = fmaf(v, v, s); }
  xx[i] = s;
}

// ============================================================ (B,D,N) -> (B,N,DP) fp16 hi/lo split
__global__ __launch_bounds__(256) void split_kernel(const float* __restrict__ xin, long bstr,
                                                    int D, int DP,
                                                    ushort_t* __restrict__ xT, long xTbstr_us) {
  __shared__ float s[32][65];
  int b = blockIdx.y;
  int n0 = blockIdx.x * 64;
  int tid = threadIdx.x;
  const float* xb = xin + (long)b * bstr;
  ushort_t* xh = xT + (long)b * xTbstr_us;
  ushort_t* xl = xh + 2048 * DP;
  for (int dc = 0; dc < DP; dc += 32) {
    for (int i = tid; i < 32 * 64; i += 256) {
      int d = i >> 6, n = i & 63;
      s[d][n] = (dc + d < D) ? xb[(long)(dc + d) * N_ + n0 + n] : 0.f;
    }
    __syncthreads();
    for (int i = tid; i < 64 * 32; i += 256) {
      int n = i >> 5, d = i & 31;
      float v = s[d][n];
      _Float16 h = (_Float16)v;
      float r1 = v - (float)h;
      _Float16 l = (_Float16)r1;
      long idx = (long)(n0 + n) * DP + dc + d;
      *(_Float16*)&xh[idx] = h;
      *(_Float16*)&xl[idx] = l;
    }
    __syncthreads();
  }
}

// ============================================================ MFMA gsa, tournament top-k:
//  block = 16 rows x 2048 cols; wave w owns cols [w*512, w*512+512) = 32 MFMA tiles 16x16x32.
//  inner = h*h + h*l + l*h (fp16-split). Per top-k iteration: per-wave 16-lane butterfly ->
//  LDS red[4][16] -> global winner per row computed uniformly by every lane -> owning wave
//  removes; each wave accumulates softmax/gather online for its 4 output rows.
template <int D, int DP, int NV>
__global__ __launch_bounds__(256) void gsa_tour_kernel(const ushort_t* __restrict__ xT,
                                                       long xTbstr_us,
                                                       const float* __restrict__ xx,
                                                       float* __restrict__ agg, long aggbstr) {
  __shared__ float red_v[4][16];
  __shared__ int red_c[4][16];
  int tid = threadIdx.x, w = tid >> 6, lane = tid & 63;
  int lo16 = lane & 15, hi4 = lane >> 4;
  int r0 = blockIdx.x * 16;
  int b = r0 >> 11, n0 = r0 & (N_ - 1);
  const ushort_t* xTb = xT + (long)b * xTbstr_us;   // h array; l at +2048*DP
  int wcol0 = w << 9;

  f32x4 acc[32];
#pragma unroll
  for (int t = 0; t < 32; ++t) acc[t] = (f32x4){0.f, 0.f, 0.f, 0.f};

  // ---- MFMA phase: D[row][col], rows = block's 16, cols = wave's 512 ----
#pragma unroll 1
  for (int ks = 0; ks < DP / 32; ++ks) {
    const ushort_t* ab = xTb + (long)(n0 + lo16) * DP + ks * 32 + hi4 * 8;
    f16x8 ah = *(const f16x8*)ab;
    f16x8 al = *(const f16x8*)(ab + 2048 * DP);
#pragma unroll
    for (int t = 0; t < 32; ++t) {
      const ushort_t* bb = xTb + (long)(wcol0 + t * 16 + lo16) * DP + ks * 32 + hi4 * 8;
      f16x8 bh = *(const f16x8*)bb;
      f16x8 bl = *(const f16x8*)(bb + 2048 * DP);
      acc[t] = __builtin_amdgcn_mfma_f32_16x16x32_f16(ah, bh, acc[t], 0, 0, 0);
      acc[t] = __builtin_amdgcn_mfma_f32_16x16x32_f16(ah, bl, acc[t], 0, 0, 0);
      acc[t] = __builtin_amdgcn_mfma_f32_16x16x32_f16(al, bh, acc[t], 0, 0, 0);
    }
  }

  // ---- dist assembly: v = 2*inner - xx[row] - xx[col]; C/D: col=lane&15, row=hi4*4+reg ----
  float xxr[4];
#pragma unroll
  for (int q = 0; q < 4; ++q) xxr[q] = xx[b * N_ + n0 + hi4 * 4 + q];
#pragma unroll
  for (int t = 0; t < 32; ++t) {
    float xxc = xx[b * N_ + wcol0 + t * 16 + lo16];
#pragma unroll
    for (int q = 0; q < 4; ++q) acc[t][q] = 2.f * acc[t][q] - xxr[q] - xxc;
  }

  // ---- chunk maxes: 8 chunks of 4 tiles per (lane, q) ----
  float m8[4][8];
  int sspack[4];
#pragma unroll
  for (int q = 0; q < 4; ++q) {
    int sp = 0;
#pragma unroll
    for (int c = 0; c < 8; ++c) {
      float mm = acc[4 * c][q]; int ss = 0;
      if (acc[4 * c + 1][q] > mm) { mm = acc[4 * c + 1][q]; ss = 1; }
      if (acc[4 * c + 2][q] > mm) { mm = acc[4 * c + 2][q]; ss = 2; }
      if (acc[4 * c + 3][q] > mm) { mm = acc[4 * c + 3][q]; ss = 3; }
      m8[q][c] = mm; sp |= ss << (2 * c);
    }
    sspack[q] = sp;
  }

  float Z[4] = {0.f, 0.f, 0.f, 0.f};
  float m0[4] = {0.f, 0.f, 0.f, 0.f};
  float ve[4][NV];
#pragma unroll
  for (int r = 0; r < 4; ++r)
#pragma unroll
    for (int vi = 0; vi < NV; ++vi) ve[r][vi] = 0.f;

  int wc_base = wcol0 + lo16;
#pragma unroll 1
  for (int it = 0; it < KNN; ++it) {
    // (1) per-(hi4,q) scan of this wave's chunk maxes
    float bv[4]; int bc[4];
#pragma unroll
    for (int q = 0; q < 4; ++q) {
      int sp = sspack[q];
      float bvq = m8[q][0]; int bcq = wc_base + ((sp & 3) << 4);
#pragma unroll
      for (int c = 1; c < 8; ++c) {
        float v = m8[q][c];
        int cc = wc_base + (c << 6) + (((sp >> (2 * c)) & 3) << 4);
        if (v > bvq) { bvq = v; bcq = cc; }
      }
      bv[q] = bvq; bc[q] = bcq;
    }
    // (2) 16-lane butterfly within hi4 group (4 rows interleaved)
#pragma unroll
    for (int off = 1; off < 16; off <<= 1) {
#pragma unroll
      for (int q = 0; q < 4; ++q) {
        float ov = __shfl_xor(bv[q], off);
        int oc = __shfl_xor(bc[q], off);
        if (ov > bv[q] || (ov == bv[q] && oc < bc[q])) { bv[q] = ov; bc[q] = oc; }
      }
    }
    // (3) publish wave maxima
    if (lo16 == 0) {
#pragma unroll
      for (int q = 0; q < 4; ++q) {
        red_v[w][hi4 * 4 + q] = bv[q];
        red_c[w][hi4 * 4 + q] = bc[q];
      }
    }
    __syncthreads();
    // (4) removal: global winner for rows hi4*4+q; owning wave removes from acc
#pragma unroll
    for (int q = 0; q < 4; ++q) {
      int row = hi4 * 4 + q;
      float gv = red_v[0][row]; int gc = red_c[0][row];
#pragma unroll
      for (int j = 1; j < 4; ++j) {
        float vj = red_v[j][row]; int cj = red_c[j][row];
        if (vj > gv || (vj == gv && cj < gc)) { gv = vj; gc = cj; }
      }
      if ((gc >> 9) == w) {
        int rel = gc - wcol0;
        int cw = rel >> 6, jw = (rel >> 4) & 3;
        bool amw = (lo16 == (rel & 15));
#pragma unroll
        for (int c = 0; c < 8; ++c)
          if (c == cw) {
#pragma unroll
            for (int j = 0; j < 4; ++j)
              if (j == jw && amw) acc[4 * c + j][q] = -3.4e38f;
            float mm = acc[4 * c][q]; int ss = 0;
            if (acc[4 * c + 1][q] > mm) { mm = acc[4 * c + 1][q]; ss = 1; }
            if (acc[4 * c + 2][q] > mm) { mm = acc[4 * c + 2][q]; ss = 2; }
            if (acc[4 * c + 3][q] > mm) { mm = acc[4 * c + 3][q]; ss = 3; }
            m8[q][c] = mm;
            sspack[q] = (sspack[q] & ~(3 << (2 * c))) | (ss << (2 * c));
          }
      }
    }
    // (5) online softmax+gather for this wave's output rows w*4+r
#pragma unroll
    for (int r = 0; r < 4; ++r) {
      int row = (w << 2) + r;
      float gv = red_v[0][row]; int gc = red_c[0][row];
#pragma unroll
      for (int j = 1; j < 4; ++j) {
        float vj = red_v[j][row]; int cj = red_c[j][row];
        if (vj > gv || (vj == gv && cj < gc)) { gv = vj; gc = cj; }
      }
      if (it == 0) m0[r] = gv;
      float e = __expf(gv - m0[r]);
      Z[r] += e;
#pragma unroll
      for (int vi = 0; vi < NV; ++vi) {
        int dd = lane + (vi << 6);
        if (D >= 64 || dd < D) {
          const ushort_t* pp = xTb + (long)gc * DP + dd;
          float xv = (float)(*(const _Float16*)pp) + (float)(*(const _Float16*)(pp + 2048 * DP));
          ve[r][vi] = fmaf(e, xv, ve[r][vi]);
        }
      }
    }
    __syncthreads();
  }

  // ---- final: agg = ve/Z - x_n ----
#pragma unroll
  for (int r = 0; r < 4; ++r) {
    float rZ = 1.f / Z[r];
    int n = n0 + (w << 2) + r;
#pragma unroll
    for (int vi = 0; vi < NV; ++vi) {
      int dd = lane + (vi << 6);
      if (D >= 64 || dd < D) {
        const ushort_t* pn = xTb + (long)n * DP + dd;
        float xn = (float)(*(const _Float16*)pn) + (float)(*(const _Float16*)(pn + 2048 * DP));
        agg[(long)b * aggbstr + (long)dd * N_ + n] = ve[r][vi] * rZ - xn;
      }
    }
  }
}

// ============================================================ small GEMM (64x64 tile) + BN stats
__global__ __launch_bounds__(256) void gemm_bn_kernel(const float* __restrict__ Wm, int O, int K,
                                                      const float* __restrict__ xin, long bstr, int Dx,
                                                      const float* __restrict__ agg, long aggbstr,
                                                      float* __restrict__ y, float* __restrict__ stats) {
  __shared__ __align__(16) float As[16][68];
  __shared__ __align__(16) float Bs[16][68];
  int tid = threadIdx.x;
  int o0 = blockIdx.x * 64;
  int j0 = blockIdx.y * 64;
  int b = j0 >> 11, n0 = j0 & (N_ - 1);
  int ty = tid >> 4, tx = tid & 15;
  float accr[4][4] = {};
  int aK = tid & 15, aO = tid >> 4;
  int bK = tid >> 4, bn4 = (tid & 15) << 2;
  for (int k0 = 0; k0 < K; k0 += 16) {
#pragma unroll
    for (int q = 0; q < 4; ++q) {
      int o = aO + (q << 4);
      As[aK][o] = (k0 + aK < K) ? Wm[(long)(o0 + o) * K + k0 + aK] : 0.f;
    }
    {
      int c = k0 + bK;
      float4 v = {0.f, 0.f, 0.f, 0.f};
      if (c < K) {
        const float* src = (c < Dx) ? xin + (long)b * bstr + (long)c * N_
                                    : agg + (long)b * aggbstr + (long)(c - Dx) * N_;
        v = *(const float4*)(src + n0 + bn4);
      }
      *(float4*)&Bs[bK][bn4] = v;
    }
    __syncthreads();
#pragma unroll
    for (int kk = 0; kk < 16; ++kk) {
      float4 a4 = *(const float4*)&As[kk][ty << 2];
      float4 b4 = *(const float4*)&Bs[kk][tx << 2];
      accr[0][0] = fmaf(a4.x, b4.x, accr[0][0]);
      accr[0][1] = fmaf(a4.x, b4.y, accr[0][1]);
      accr[0][2] = fmaf(a4.x, b4.z, accr[0][2]);
      accr[0][3] = fmaf(a4.x, b4.w, accr[0][3]);
      accr[1][0] = fmaf(a4.y, b4.x, accr[1][0]);
      accr[1][1] = fmaf(a4.y, b4.y, accr[1][1]);
      accr[1][2] = fmaf(a4.y, b4.z, accr[1][2]);
      accr[1][3] = fmaf(a4.y, b4.w, accr[1][3]);
      accr[2][0] = fmaf(a4.z, b4.x, accr[2][0]);
      accr[2][1] = fmaf(a4.z, b4.y, accr[2][1]);
      accr[2][2] = fmaf(a4.z, b4.z, accr[2][2]);
      accr[2][3] = fmaf(a4.z, b4.w, accr[2][3]);
      accr[3][0] = fmaf(a4.w, b4.x, accr[3][0]);
      accr[3][1] = fmaf(a4.w, b4.y, accr[3][1]);
      accr[3][2] = fmaf(a4.w, b4.z, accr[3][2]);
      accr[3][3] = fmaf(a4.w, b4.w, accr[3][3]);
    }
    __syncthreads();
  }
#pragma unroll
  for (int r = 0; r < 4; ++r) {
    int o = o0 + (ty << 2) + r;
    float4 v;
    v.x = accr[r][0]; v.y = accr[r][1]; v.z = accr[r][2]; v.w = accr[r][3];
    *(float4*)(y + ((long)b * O + o) * N_ + n0 + bn4) = v;
    float s1 = v.x + v.y + v.z + v.w;
    float s2 = v.x * v.x + v.y * v.y + v.z * v.z + v.w * v.w;
#pragma unroll
    for (int off = 1; off < 16; off <<= 1) { s1 += __shfl_xor(s1, off); s2 += __shfl_xor(s2, off); }
    if (tx == 0) { atomicAdd(&stats[o], s1); atomicAdd(&stats[O + o], s2); }
  }
}

// ============================================================ big GEMM (128x128x8 tile) + BN stats
__global__ __launch_bounds__(256) void gemm_bn128_kernel(const float* __restrict__ Wm, int O, int K,
                                                         const float* __restrict__ xin, long bstr, int Dx,
                                                         const float* __restrict__ agg, long aggbstr,
                                                         float* __restrict__ y, float* __restrict__ stats) {
  __shared__ __align__(16) float As[8][132];
  __shared__ __align__(16) float Bs[8][132];
  int tid = threadIdx.x;
  int o0 = blockIdx.x * 128;
  int j0 = blockIdx.y * 128;
  int b = j0 >> 11, n0 = j0 & (N_ - 1);
  int ty = tid >> 4, tx = tid & 15;
  float acc[8][8] = {};
  int aO = tid & 127, aKb = tid >> 7;
  int bK = tid >> 5, bj4 = (tid & 31) << 2;
#pragma unroll 1
  for (int k0 = 0; k0 < K; k0 += 8) {
    __syncthreads();
#pragma unroll
    for (int q = 0; q < 4; ++q) {
      int kk = aKb + (q << 1);
      As[kk][aO] = Wm[(long)(o0 + aO) * K + k0 + kk];
    }
    {
      int c = k0 + bK;
      const float* src = (c < Dx) ? xin + (long)b * bstr + (long)c * N_
                                  : agg + (long)b * aggbstr + (long)(c - Dx) * N_;
      *(float4*)&Bs[bK][bj4] = *(const float4*)(src + n0 + bj4);
    }
    __syncthreads();
#pragma unroll
    for (int kk = 0; kk < 8; ++kk) {
      float4 alo = *(const float4*)&As[kk][ty << 2];
      float4 ahi = *(const float4*)&As[kk][64 + (ty << 2)];
      float4 blo = *(const float4*)&Bs[kk][tx << 2];
      float4 bhi = *(const float4*)&Bs[kk][64 + (tx << 2)];
      float av[8] = {alo.x, alo.y, alo.z, alo.w, ahi.x, ahi.y, ahi.z, ahi.w};
      float bv[8] = {blo.x, blo.y, blo.z, blo.w, bhi.x, bhi.y, bhi.z, bhi.w};
#pragma unroll
      for (int r = 0; r < 8; ++r)
#pragma unroll
        for (int c = 0; c < 8; ++c) acc[r][c] = fmaf(av[r], bv[c], acc[r][c]);
    }
  }
#pragma unroll
  for (int r = 0; r < 8; ++r) {
    int o = o0 + ((r < 4) ? (ty << 2) + r : 64 + (ty << 2) + (r - 4));
    float4 vlo, vhi;
    vlo.x = acc[r][0]; vlo.y = acc[r][1]; vlo.z = acc[r][2]; vlo.w = acc[r][3];
    vhi.x = acc[r][4]; vhi.y = acc[r][5]; vhi.z = acc[r][6]; vhi.w = acc[r][7];
    float* yrow = y + ((long)b * O + o) * N_ + n0;
    *(float4*)(yrow + (tx << 2)) = vlo;
    *(float4*)(yrow + 64 + (tx << 2)) = vhi;
    float s1 = vlo.x + vlo.y + vlo.z + vlo.w + vhi.x + vhi.y + vhi.z + vhi.w;
    float s2 = vlo.x * vlo.x + vlo.y * vlo.y + vlo.z * vlo.z + vlo.w * vlo.w +
               vhi.x * vhi.x + vhi.y * vhi.y + vhi.z * vhi.z + vhi.w * vhi.w;
#pragma unroll
    for (int off = 1; off < 16; off <<= 1) { s1 += __shfl_xor(s1, off); s2 += __shfl_xor(s2, off); }
    if (tx == 0) { atomicAdd(&stats[o], s1); atomicAdd(&stats[O + o], s2); }
  }
}

// ============================================================ fold BN stats into scale/shift
__global__ __launch_bounds__(256) void bn_finalize_kernel(float* __restrict__ stats,
                                                          const float* __restrict__ g,
                                                          const float* __restrict__ be, int O) {
  int o = blockIdx.x * 256 + threadIdx.x;
  if (o >= O) return;
  const float inv_cnt = 1.f / (B_ * (float)N_);
  float mean = stats[o] * inv_cnt;
  float var = stats[O + o] * inv_cnt - mean * mean;
  float a = g[o] * rsqrtf(var + BN_EPS);
  float bb = be[o] - mean * a;
  stats[o] = a;
  stats[O + o] = bb;
}

// ============================================================ y -> lrelu(a*y+b) -> dst (+dst2)
__global__ __launch_bounds__(256) void bn_apply_kernel(const float* __restrict__ y,
                                                       const float* __restrict__ stats, int O,
                                                       float* __restrict__ dst, int c0, int dstStride,
                                                       float* __restrict__ dst2) {
  long i4 = (long)blockIdx.x * 256 + threadIdx.x;
  long total4 = (long)B_ * O * N_ / 4;
  if (i4 >= total4) return;
  long i = i4 << 2;
  int ob = __ffs(O) - 1;
  int o = (int)((i >> 11) & (O - 1));
  int b = (int)(i >> (11 + ob));
  int n = (int)(i & (N_ - 1));
  float a = stats[o], bb = stats[O + o];
  float4 v = *(const float4*)(y + i);
  v.x = fmaf(a, v.x, bb); v.x = v.x >= 0.f ? v.x : SLOPE * v.x;
  v.y = fmaf(a, v.y, bb); v.y = v.y >= 0.f ? v.y : SLOPE * v.y;
  v.z = fmaf(a, v.z, bb); v.z = v.z >= 0.f ? v.z : SLOPE * v.z;
  v.w = fmaf(a, v.w, bb); v.w = v.w >= 0.f ? v.w : SLOPE * v.w;
  *(float4*)(dst + ((long)b * dstStride + c0 + o) * N_ + n) = v;
  if (dst2) *(float4*)(dst2 + i) = v;
}

// ============================================================ launcher
extern "C" void kernel_launch(void* const* d_in, const int* in_sizes, int n_in,
                              void* d_out, int out_size, void* d_ws, size_t ws_size,
                              hipStream_t stream) {
  const float* x = (const float*)d_in[0];
  const float* W[5];
  const float* gm[5];
  const float* bt[5];
  for (int i = 0; i < 5; ++i) W[i] = (const float*)d_in[1 + i];
  for (int i = 0; i < 5; ++i) { gm[i] = (const float*)d_in[6 + 2 * i]; bt[i] = (const float*)d_in[7 + 2 * i]; }

  const long XBS = 512L * N_;                     // xall per-batch stride (floats)
  float* xall = (float*)d_ws;                     // (B, 512, N): x1@ch0, x2@ch64, x3@ch128, x4@ch256
  float* xxb = xall + (long)B_ * XBS;             // (B, N)
  float* stats = xxb + (long)B_ * N_;             // 5 * 1024
  // fp16-split transpose pair lives in xall ch256..383 (1 MB/batch at DP=128);
  // agg lives in ch384..511. Both dead before L4's bn_apply writes x4 there.
  ushort_t* xTbase = (ushort_t*)(xall + 256L * N_);
  const long xTbstr_us = XBS * 2;                 // per-batch advance in ushorts
  float* aggb = xall + 384L * N_;
  float* yb = (float*)d_out;                      // (B, O, N), max = x5 slot exactly
  float* outB = (float*)d_out + (long)B_ * XBS;   // x3 output slot

  hipMemsetAsync(stats, 0, 5 * 1024 * sizeof(float), stream);

  struct LayerCfg { const float* xin; long bstr; int D; int DP; int O; int c0; };
  LayerCfg L[4] = {
      {x, 3L * N_, 3, 32, 64, 0},
      {xall, XBS, 64, 64, 64, 64},
      {xall + 64L * N_, XBS, 64, 64, 128, 128},
      {xall + 128L * N_, XBS, 128, 128, 256, 256},
  };

  for (int li = 0; li < 4; ++li) {
    const LayerCfg c = L[li];
    float* st = stats + li * 1024;
    xx_kernel<<<B_ * N_ / 256, 256, 0, stream>>>(c.xin, c.bstr, c.D, xxb);
    split_kernel<<<dim3(N_ / 64, B_), 256, 0, stream>>>(c.xin, c.bstr, c.D, c.DP, xTbase, xTbstr_us);
    if (c.D == 3)
      gsa_tour_kernel<3, 32, 1><<<B_ * N_ / 16, 256, 0, stream>>>(xTbase, xTbstr_us, xxb, aggb, XBS);
    else if (c.D == 64)
      gsa_tour_kernel<64, 64, 1><<<B_ * N_ / 16, 256, 0, stream>>>(xTbase, xTbstr_us, xxb, aggb, XBS);
    else
      gsa_tour_kernel<128, 128, 2><<<B_ * N_ / 16, 256, 0, stream>>>(xTbase, xTbstr_us, xxb, aggb, XBS);
    int K = 2 * c.D;
    if (c.O >= 128 && (K % 8) == 0)
      gemm_bn128_kernel<<<dim3(c.O / 128, B_ * N_ / 128), 256, 0, stream>>>(
          W[li], c.O, K, c.xin, c.bstr, c.D, aggb, XBS, yb, st);
    else
      gemm_bn_kernel<<<dim3(c.O / 64, B_ * N_ / 64), 256, 0, stream>>>(
          W[li], c.O, K, c.xin, c.bstr, c.D, aggb, XBS, yb, st);
    bn_finalize_kernel<<<(c.O + 255) / 256, 256, 0, stream>>>(st, gm[li], bt[li], c.O);
    long t4 = (long)B_ * c.O * N_ / 4;
    bn_apply_kernel<<<(int)((t4 + 255) / 256), 256, 0, stream>>>(
        yb, st, c.O, xall, c.c0, 512, (li == 2) ? outB : nullptr);
  }
  // layer 5: plain conv on the concat (xall ch0..511), no gsa
  {
    float* st = stats + 4 * 1024;
    gemm_bn128_kernel<<<dim3(512 / 128, B_ * N_ / 128), 256, 0, stream>>>(
        W[4], 512, 512, xall, XBS, 512, nullptr, XBS, yb, st);
    bn_finalize_kernel<<<2, 256, 0, stream>>>(st, gm[4], bt[4], 512);
    long t4 = (long)B_ * 512 * N_ / 4;
    bn_apply_kernel<<<(int)((t4 + 255) / 256), 256, 0, stream>>>(yb, st, 512, yb, 0, 512, nullptr);
  }
}